// Round 15
// baseline (301.396 us; speedup 1.0000x reference)
//
#include <hip/hip_runtime.h>
#include <hip/hip_bf16.h>
#include <hip/hip_cooperative_groups.h>

namespace cg = cooperative_groups;

typedef unsigned short u16;
typedef short bf16x8 __attribute__((ext_vector_type(8)));
typedef float f32x4 __attribute__((ext_vector_type(4)));

#define NROWS 8192
#define EMBD  1140
#define FDIM  3968
#define N1R   1000
#define N1P   1024
#define N2R   100
#define N2P   128
#define DG    512

__device__ inline u16 f2b(float f) {
  __hip_bfloat16 h = __float2bfloat16(f);
  return *reinterpret_cast<u16*>(&h);
}

__device__ inline float b2f(u16 u) {
  unsigned v = (unsigned)u << 16;
  union { unsigned u; float f; } c;
  c.u = v;
  return c.f;
}

__device__ inline float tanh_fast(float x) {
  float ax = fabsf(x);
  float t = __expf(-2.f * ax);
  float r = (1.f - t) / (1.f + t);
  return x < 0.f ? -r : r;
}

__device__ inline void gld16(const void* g, void* l) {
  __builtin_amdgcn_global_load_lds(
      (const __attribute__((address_space(1))) unsigned int*)g,
      (__attribute__((address_space(3))) unsigned int*)l, 16, 0, 0);
}

// =========================================================================
// Shared phase bodies (used by both the mega kernel and fallback kernels).
// t is the 256-thread index within a (virtual) block; smem is a 64KB slice.
// =========================================================================

__device__ void prep_body(int b, int t, char* smem,
    const float* __restrict__ W1, const float* __restrict__ W2,
    const float* __restrict__ Wg, const float* __restrict__ We,
    const float* __restrict__ H_emb, const float* __restrict__ conv_w,
    const float* __restrict__ conv_b,
    u16* __restrict__ W1bf, u16* __restrict__ W2bf,
    u16* __restrict__ Wgbf, u16* __restrict__ Webf,
    u16* __restrict__ Abuf, u16* __restrict__ Bbuf) {
  if (b < 2112) {
    const float* src;
    u16* dst;
    int row, c8, realRow, realCol;
    if (b < 1984) {
      int id = b * 256 + t;
      row = id / 496; c8 = (id - row * 496) * 8;
      src = W1 + (size_t)row * FDIM + c8;
      dst = W1bf + (size_t)row * FDIM + c8;
      realRow = N1R; realCol = FDIM;
    } else if (b < 2048) {
      int id = (b - 1984) * 256 + t;
      row = id >> 7; c8 = (id & 127) * 8;
      src = W2 + (size_t)row * N1R + c8;
      dst = W2bf + (size_t)row * N1P + c8;
      realRow = N2R; realCol = N1R;
    } else if (b < 2080) {
      int id = (b - 2048) * 256 + t;
      row = id >> 6; c8 = (id & 63) * 8;
      src = Wg + (size_t)row * DG + c8;
      dst = Wgbf + (size_t)row * DG + c8;
      realRow = N2R; realCol = DG;
    } else {
      int id = (b - 2080) * 256 + t;
      row = id >> 6; c8 = (id & 63) * 8;
      src = We + (size_t)row * DG + c8;
      dst = Webf + (size_t)row * DG + c8;
      realRow = N2R; realCol = DG;
    }
    bf16x8 o = (bf16x8){0, 0, 0, 0, 0, 0, 0, 0};
    if (row < realRow && c8 < realCol) {
#pragma unroll
      for (int j = 0; j < 8; ++j) o[j] = (short)f2b(src[j]);
    }
    *(bf16x8*)dst = o;
    return;
  }
  float* se = (float*)smem;
  float* sw = se + 1152;
  float* sb = sw + 800;
  const int eb = b - 2112;
  bool isA = eb < 240;
  const float* emb = H_emb + (size_t)eb * EMBD;
  u16* outp = isA ? (Abuf + (size_t)eb * FDIM) : (Bbuf + (size_t)(eb - 240) * FDIM);
  for (int i = t; i < EMBD; i += 256) se[i] = emb[i];
  int kh = isA ? 0 : 1;
  for (int i = t; i < 800; i += 256) {
    int o = i / 25, kw = i - o * 25;
    sw[i] = conv_w[o * 50 + kh * 25 + kw];
  }
  if (t < 32) sb[t] = isA ? conv_b[t] : 0.f;
  __syncthreads();   // both halves take this branch together (verified: no mixed block)
  for (int f = t; f < FDIM; f += 256) {
    int o = f / 124, wpos = f - o * 124;
    const float* e = se + wpos * 9;
    const float* wp = sw + o * 25;
    float acc = sb[o];
#pragma unroll
    for (int kw = 0; kw < 25; ++kw) acc += wp[kw] * e[kw];
    outp[f] = f2b(acc);
  }
}

__device__ void cc_body(int r, int t,
    const u16* __restrict__ Abuf, const u16* __restrict__ Bbuf,
    const int* __restrict__ xi, const int* __restrict__ yi, u16* __restrict__ cbf) {
  const bf16x8* pa = (const bf16x8*)(Abuf + (size_t)xi[r] * FDIM);
  const bf16x8* pb = (const bf16x8*)(Bbuf + (size_t)yi[r] * FDIM);
  bf16x8* out = (bf16x8*)(cbf + (size_t)r * FDIM);
  for (int i = t; i < FDIM / 8; i += 256) {
    bf16x8 a = pa[i], b = pb[i];
    bf16x8 o;
#pragma unroll
    for (int j = 0; j < 8; ++j) {
      float v = b2f((u16)a[j]) + b2f((u16)b[j]);
      v = v > 0.f ? v : 0.01f * v;
      o[j] = (short)f2b(v);
    }
    out[i] = o;
  }
}

// fc1 tile body (r7-proven): vb in [0,512) selects the 128x128 tile.
__device__ void fc1_body(int vb, int t, char* smem,
    const u16* __restrict__ A, const u16* __restrict__ B,
    const float* __restrict__ bias, u16* __restrict__ C) {
  u16* AsP = (u16*)smem;           // [2][8192]
  u16* BsP = AsP + 16384;
  const int wg = (vb & 7) * 64 + (vb >> 3);   // XCD-chunked swizzle
  const int tm = (wg / 8) * 128;
  const int tn = (wg % 8) * 128;
  const int K = FDIM;

  const int lane = t & 63;
  const int w = t >> 6;
  const int wr = (w >> 1) * 64, wc = (w & 1) * 64;
  const int fr = lane & 15;
  const int kg = lane >> 4;

  const int srow = lane >> 3;
  const int su = ((lane & 7) ^ srow) * 8;
  const u16* gA[4];
  const u16* gB[4];
  int ldsOff[4];
#pragma unroll
  for (int i = 0; i < 4; ++i) {
    const int c = w + i * 4;
    gA[i] = A + (size_t)(tm + c * 8 + srow) * K + su;
    gB[i] = B + (size_t)(tn + c * 8 + srow) * K + su;
    ldsOff[i] = c * 512;
  }

  f32x4 acc[4][4];
#pragma unroll
  for (int m = 0; m < 4; ++m)
#pragma unroll
    for (int n = 0; n < 4; ++n) acc[m][n] = (f32x4){0.f, 0.f, 0.f, 0.f};

  const int nk = K >> 6;
#pragma unroll
  for (int i = 0; i < 4; ++i) {
    gld16(gA[i], AsP + ldsOff[i]);
    gld16(gB[i], BsP + ldsOff[i]);
  }
  __syncthreads();

  for (int kt = 0; kt < nk; ++kt) {
    const int cb = kt & 1;
    if (kt + 1 < nk) {
      const int ko = (kt + 1) << 6;
#pragma unroll
      for (int i = 0; i < 4; ++i) {
        gld16(gA[i] + ko, AsP + (cb ^ 1) * 8192 + ldsOff[i]);
        gld16(gB[i] + ko, BsP + (cb ^ 1) * 8192 + ldsOff[i]);
      }
    }
    __builtin_amdgcn_sched_barrier(0);
#pragma unroll
    for (int ks = 0; ks < 2; ++ks) {
      const int un = ((ks * 4 + kg) ^ (fr & 7)) << 4;
      bf16x8 af[4], bff[4];
#pragma unroll
      for (int m = 0; m < 4; ++m)
        af[m] = *(const bf16x8*)((const char*)(AsP + cb * 8192) + (wr + m * 16 + fr) * 128 + un);
#pragma unroll
      for (int n = 0; n < 4; ++n)
        bff[n] = *(const bf16x8*)((const char*)(BsP + cb * 8192) + (wc + n * 16 + fr) * 128 + un);
#pragma unroll
      for (int m = 0; m < 4; ++m)
#pragma unroll
        for (int n = 0; n < 4; ++n)
          acc[m][n] = __builtin_amdgcn_mfma_f32_16x16x32_bf16(af[m], bff[n], acc[m][n], 0, 0, 0);
    }
    __syncthreads();
  }

#pragma unroll
  for (int n = 0; n < 4; ++n) {
    int col = tn + wc + n * 16 + fr;
    float bv = (col < N1R) ? bias[col] : 0.f;
#pragma unroll
    for (int m = 0; m < 4; ++m) {
#pragma unroll
      for (int j = 0; j < 4; ++j) {
        int row = tm + wr + m * 16 + kg * 4 + j;
        float v = acc[m][n][j] + bv;
        v = v > 0.f ? v : 0.01f * v;
        C[(size_t)row * N1P + col] = f2b(v);
      }
    }
  }
}

// tail v4 body (r10-proven): vb in [0,512) selects the 16-row group.
__device__ void tail_body(int vb, int t, char* smem,
    const u16* __restrict__ hfc1, const u16* __restrict__ W2bf, const float* __restrict__ b2,
    const float* __restrict__ ldg, const float* __restrict__ lde,
    const u16* __restrict__ Wgbf, const float* __restrict__ bg,
    const u16* __restrict__ Webf, const float* __restrict__ be,
    float* __restrict__ out0, float* __restrict__ out1) {
  float (*H16)[16] = (float(*)[16])smem;        // [128][16]
  float* dpart = (float*)(smem + 8192);         // [8][16]
  float* wt = (float*)(smem + 8704);            // [2][16]

  const int tm = vb * 16;
  const int lane = t & 63;
  const int w = t >> 6;
  const int fr = lane & 15;
  const int kg = lane >> 4;
  const int n0 = w * 2;

  {
    f32x4 a0e = (f32x4){0.f, 0.f, 0.f, 0.f}, a0o = a0e, a1e = a0e, a1o = a0e;
    const u16* Ap = hfc1 + (size_t)(tm + fr) * N1P + kg * 8;
    const u16* B0 = W2bf + (size_t)(n0 * 16 + fr) * N1P + kg * 8;
    const u16* B1 = B0 + (size_t)16 * N1P;
#pragma unroll 4
    for (int k2 = 0; k2 < 16; ++k2) {
      bf16x8 afe = *(const bf16x8*)(Ap + k2 * 64);
      bf16x8 afo = *(const bf16x8*)(Ap + k2 * 64 + 32);
      bf16x8 f0e = *(const bf16x8*)(B0 + k2 * 64);
      bf16x8 f0o = *(const bf16x8*)(B0 + k2 * 64 + 32);
      bf16x8 f1e = *(const bf16x8*)(B1 + k2 * 64);
      bf16x8 f1o = *(const bf16x8*)(B1 + k2 * 64 + 32);
      a0e = __builtin_amdgcn_mfma_f32_16x16x32_bf16(afe, f0e, a0e, 0, 0, 0);
      a1e = __builtin_amdgcn_mfma_f32_16x16x32_bf16(afe, f1e, a1e, 0, 0, 0);
      a0o = __builtin_amdgcn_mfma_f32_16x16x32_bf16(afo, f0o, a0o, 0, 0, 0);
      a1o = __builtin_amdgcn_mfma_f32_16x16x32_bf16(afo, f1o, a1o, 0, 0, 0);
    }
#pragma unroll
    for (int n = 0; n < 2; ++n) {
      int col = (n0 + n) * 16 + fr;
      float bv = (col < N2R) ? b2[col] : 0.f;
      f32x4 o;
#pragma unroll
      for (int j = 0; j < 4; ++j) {
        float x = (n == 0 ? a0e[j] + a0o[j] : a1e[j] + a1o[j]) + bv;
        o[j] = x > 0.f ? x : 0.01f * x;
      }
      *(f32x4*)&H16[col][kg * 4] = o;
    }
  }
  __syncthreads();

#pragma unroll 1
  for (int sec = 0; sec < 2; ++sec) {
    const float* ld = sec == 0 ? ldg : lde;
    const u16* Wb = sec == 0 ? Wgbf : Webf;
    const float* bb = sec == 0 ? bg : be;

    f32x4 a0e = (f32x4){0.f, 0.f, 0.f, 0.f}, a0o = a0e, a1e = a0e, a1o = a0e;
    const float* Ap = ld + (size_t)(tm + fr) * DG + kg * 8;
    const u16* B0 = Wb + (size_t)(n0 * 16 + fr) * DG + kg * 8;
    const u16* B1 = B0 + (size_t)16 * DG;
#pragma unroll 2
    for (int k2 = 0; k2 < 8; ++k2) {
      float4 v0 = *(const float4*)(Ap + k2 * 64);
      float4 v1 = *(const float4*)(Ap + k2 * 64 + 4);
      float4 v2 = *(const float4*)(Ap + k2 * 64 + 32);
      float4 v3 = *(const float4*)(Ap + k2 * 64 + 36);
      bf16x8 afe, afo;
      afe[0] = (short)f2b(v0.x); afe[1] = (short)f2b(v0.y);
      afe[2] = (short)f2b(v0.z); afe[3] = (short)f2b(v0.w);
      afe[4] = (short)f2b(v1.x); afe[5] = (short)f2b(v1.y);
      afe[6] = (short)f2b(v1.z); afe[7] = (short)f2b(v1.w);
      afo[0] = (short)f2b(v2.x); afo[1] = (short)f2b(v2.y);
      afo[2] = (short)f2b(v2.z); afo[3] = (short)f2b(v2.w);
      afo[4] = (short)f2b(v3.x); afo[5] = (short)f2b(v3.y);
      afo[6] = (short)f2b(v3.z); afo[7] = (short)f2b(v3.w);
      bf16x8 f0e = *(const bf16x8*)(B0 + k2 * 64);
      bf16x8 f0o = *(const bf16x8*)(B0 + k2 * 64 + 32);
      bf16x8 f1e = *(const bf16x8*)(B1 + k2 * 64);
      bf16x8 f1o = *(const bf16x8*)(B1 + k2 * 64 + 32);
      a0e = __builtin_amdgcn_mfma_f32_16x16x32_bf16(afe, f0e, a0e, 0, 0, 0);
      a1e = __builtin_amdgcn_mfma_f32_16x16x32_bf16(afe, f1e, a1e, 0, 0, 0);
      a0o = __builtin_amdgcn_mfma_f32_16x16x32_bf16(afo, f0o, a0o, 0, 0, 0);
      a1o = __builtin_amdgcn_mfma_f32_16x16x32_bf16(afo, f1o, a1o, 0, 0, 0);
    }
    float dv[4] = {0.f, 0.f, 0.f, 0.f};
#pragma unroll
    for (int n = 0; n < 2; ++n) {
      int col = (n0 + n) * 16 + fr;
      float bv = (col < N2R) ? bb[col] : 0.f;
      f32x4 h = *(const f32x4*)&H16[col][kg * 4];
#pragma unroll
      for (int j = 0; j < 4; ++j) {
        float s = (n == 0 ? a0e[j] + a0o[j] : a1e[j] + a1o[j]) + bv;
        dv[j] += tanh_fast(s) * h[j];
      }
    }
#pragma unroll
    for (int j = 0; j < 4; ++j) {
      float v = dv[j];
      v += __shfl_xor(v, 1);
      v += __shfl_xor(v, 2);
      v += __shfl_xor(v, 4);
      v += __shfl_xor(v, 8);
      dv[j] = v;
    }
    if (fr == 0) {
#pragma unroll
      for (int j = 0; j < 4; ++j) dpart[(sec * 4 + w) * 16 + kg * 4 + j] = dv[j];
    }
  }
  __syncthreads();

  if (t < 16) {
    float ag = dpart[0 + t] + dpart[16 + t] + dpart[32 + t] + dpart[48 + t];
    float ae = dpart[64 + t] + dpart[80 + t] + dpart[96 + t] + dpart[112 + t];
    float mm = fmaxf(ag, ae);
    float eg = __expf(ag - mm), eo = __expf(ae - mm);
    float inv = 1.f / (eg + eo);
    wt[t] = eg * inv;
    wt[16 + t] = eo * inv;
  }
  __syncthreads();

  for (int i = t; i < 16 * (DG / 4); i += 256) {
    int r = i >> 7, c = i & 127;
    float w0 = wt[r], w1 = wt[16 + r];
    size_t off = (size_t)(tm + r) * DG + c * 4;
    float4 a = *(const float4*)(ldg + off);
    a.x *= w0; a.y *= w0; a.z *= w0; a.w *= w0;
    *(float4*)(out0 + off) = a;
    float4 b = *(const float4*)(lde + off);
    b.x *= w1; b.y *= w1; b.z *= w1; b.w *= w1;
    *(float4*)(out1 + off) = b;
  }
}

// =========================================================================
// MEGA: 256 blocks x 512 threads, 128KB dynamic LDS; each block = 2 halves,
// each half = one 256-thread virtual block with a private 64KB smem slice.
// =========================================================================
__global__ __launch_bounds__(512) void mega_kernel(
    const float* __restrict__ W1, const float* __restrict__ W2,
    const float* __restrict__ Wg, const float* __restrict__ We,
    const float* __restrict__ H_emb, const float* __restrict__ conv_w,
    const float* __restrict__ conv_b,
    u16* __restrict__ W1bf, u16* __restrict__ W2bf,
    u16* __restrict__ Wgbf, u16* __restrict__ Webf,
    u16* __restrict__ Abuf, u16* __restrict__ Bbuf,
    const int* __restrict__ xi, const int* __restrict__ yi,
    u16* __restrict__ cbf, const float* __restrict__ b1, u16* __restrict__ hfc1,
    const float* __restrict__ ldg, const float* __restrict__ lde,
    const float* __restrict__ b2, const float* __restrict__ bg,
    const float* __restrict__ be,
    float* __restrict__ out0, float* __restrict__ out1) {
  extern __shared__ __align__(16) char smem_dyn[];
  cg::grid_group grid = cg::this_grid();
  const int t512 = threadIdx.x;
  const int half = t512 >> 8;
  const int t = t512 & 255;
  const int bid = blockIdx.x;
  char* smem = smem_dyn + half * 65536;

  // phase 0: prep — virtual block vb = 2*bid+half (branch-uniform per block; verified)
  {
    const int vb = bid * 2 + half;
#pragma unroll 1
    for (int it = 0; it < 6; ++it) {
      int b = vb + it * 512;
      if (b < 2756)
        prep_body(b, t, smem, W1, W2, Wg, We, H_emb, conv_w, conv_b,
                  W1bf, W2bf, Wgbf, Webf, Abuf, Bbuf);
      __syncthreads();   // all 512 threads reach; guards smem reuse
    }
  }
  grid.sync();

  // phase 1: conv_combine
  {
    const int vb = bid * 2 + half;
#pragma unroll 1
    for (int r = vb; r < NROWS; r += 512)
      cc_body(r, t, Abuf, Bbuf, xi, yi, cbf);
  }
  grid.sync();

  // phase 2: fc1 — vb = bid + half*256 keeps both half-tiles in one XCD chunk
  fc1_body(bid + half * 256, t, smem, cbf, W1bf, b1, hfc1);
  grid.sync();

  // phase 3: tail
  tail_body(bid * 2 + half, t, smem, hfc1, W2bf, b2, ldg, lde,
            Wgbf, bg, Webf, be, out0, out1);
}

// =========================================================================
// Fallback standalone kernels (r10-proven 4-launch path)
// =========================================================================
__global__ __launch_bounds__(256) void prep_kernel(
    const float* __restrict__ W1, const float* __restrict__ W2,
    const float* __restrict__ Wg, const float* __restrict__ We,
    const float* __restrict__ H_emb, const float* __restrict__ conv_w,
    const float* __restrict__ conv_b,
    u16* __restrict__ W1bf, u16* __restrict__ W2bf,
    u16* __restrict__ Wgbf, u16* __restrict__ Webf,
    u16* __restrict__ Abuf, u16* __restrict__ Bbuf) {
  __shared__ __align__(16) char smem[8192];
  prep_body(blockIdx.x, threadIdx.x, smem, W1, W2, Wg, We, H_emb, conv_w, conv_b,
            W1bf, W2bf, Wgbf, Webf, Abuf, Bbuf);
}

__global__ __launch_bounds__(256) void conv_combine_kernel(
    const u16* __restrict__ Abuf, const u16* __restrict__ Bbuf,
    const int* __restrict__ xi, const int* __restrict__ yi, u16* __restrict__ cbf) {
  cc_body(blockIdx.x, threadIdx.x, Abuf, Bbuf, xi, yi, cbf);
}

__global__ __launch_bounds__(256) void fc1_kernel(
    const u16* __restrict__ A, const u16* __restrict__ B,
    const float* __restrict__ bias, u16* __restrict__ C) {
  __shared__ __align__(16) char smem[65536];
  fc1_body(blockIdx.x, threadIdx.x, smem, A, B, bias, C);
}

__global__ __launch_bounds__(256) void tail_kernel(
    const u16* __restrict__ hfc1, const u16* __restrict__ W2bf, const float* __restrict__ b2,
    const float* __restrict__ ldg, const float* __restrict__ lde,
    const u16* __restrict__ Wgbf, const float* __restrict__ bg,
    const u16* __restrict__ Webf, const float* __restrict__ be,
    float* __restrict__ out0, float* __restrict__ out1) {
  __shared__ __align__(16) char smem[8704 + 128];
  tail_body(blockIdx.x, threadIdx.x, smem, hfc1, W2bf, b2, ldg, lde,
            Wgbf, bg, Webf, be, out0, out1);
}

extern "C" void kernel_launch(void* const* d_in, const int* in_sizes, int n_in,
                              void* d_out, int out_size, void* d_ws, size_t ws_size,
                              hipStream_t stream) {
  const float* ld_gcn = (const float*)d_in[0];
  const float* ld_enc = (const float*)d_in[1];
  const int*   xi     = (const int*)d_in[2];
  const int*   yi     = (const int*)d_in[3];
  const float* H_emb  = (const float*)d_in[4];
  const float* conv_w = (const float*)d_in[5];
  const float* conv_b = (const float*)d_in[6];
  const float* W1     = (const float*)d_in[7];
  const float* b1     = (const float*)d_in[8];
  const float* W2     = (const float*)d_in[9];
  const float* b2     = (const float*)d_in[10];
  const float* Wg     = (const float*)d_in[11];
  const float* bg     = (const float*)d_in[12];
  const float* We     = (const float*)d_in[13];
  const float* be     = (const float*)d_in[14];

  char* ws = (char*)d_ws;
  size_t off = 0;
  auto alloc = [&](size_t bytes) -> void* {
    void* p = ws + off;
    off = (off + bytes + 255) & ~(size_t)255;
    return p;
  };
  u16* Abuf = (u16*)alloc(240ull * FDIM * 2);
  u16* Bbuf = (u16*)alloc(404ull * FDIM * 2);
  u16* cbf  = (u16*)alloc((size_t)NROWS * FDIM * 2);
  u16* W1bf = (u16*)alloc((size_t)N1P * FDIM * 2);
  u16* W2bf = (u16*)alloc((size_t)N2P * N1P * 2);
  u16* Wgbf = (u16*)alloc((size_t)N2P * DG * 2);
  u16* Webf = (u16*)alloc((size_t)N2P * DG * 2);
  u16* hfc1 = (u16*)alloc((size_t)NROWS * N1P * 2);
  if (ws_size < off) return;  // ~96 MB needed

  float* out0 = (float*)d_out;
  float* out1 = out0 + (size_t)NROWS * DG;

  hipFuncSetAttribute((const void*)mega_kernel,
                      hipFuncAttributeMaxDynamicSharedMemorySize, 131072);

  void* args[] = {
    (void*)&W1, (void*)&W2, (void*)&Wg, (void*)&We, (void*)&H_emb,
    (void*)&conv_w, (void*)&conv_b,
    (void*)&W1bf, (void*)&W2bf, (void*)&Wgbf, (void*)&Webf,
    (void*)&Abuf, (void*)&Bbuf,
    (void*)&xi, (void*)&yi, (void*)&cbf, (void*)&b1, (void*)&hfc1,
    (void*)&ld_gcn, (void*)&ld_enc, (void*)&b2, (void*)&bg, (void*)&be,
    (void*)&out0, (void*)&out1
  };
  hipError_t err = hipLaunchCooperativeKernel((void*)mega_kernel, dim3(256), dim3(512),
                                              args, 131072, stream);
  if (err != hipSuccess) {
    // deterministic fallback: proven 4-launch path (r10)
    prep_kernel<<<2756, 256, 0, stream>>>(W1, W2, Wg, We, H_emb, conv_w, conv_b,
                                          W1bf, W2bf, Wgbf, Webf, Abuf, Bbuf);
    conv_combine_kernel<<<NROWS, 256, 0, stream>>>(Abuf, Bbuf, xi, yi, cbf);
    fc1_kernel<<<512, 256, 0, stream>>>(cbf, W1bf, b1, hfc1);
    tail_kernel<<<512, 256, 0, stream>>>(hfc1, W2bf, b2, ld_gcn, ld_enc,
                                         Wgbf, bg, Webf, be, out0, out1);
  }
}